// Round 5
// baseline (254.779 us; speedup 1.0000x reference)
//
#include <hip/hip_runtime.h>
#include <hip/hip_bf16.h>

// Problem constants (reference: N=16384, C=2048, F=512; fp32 in/out).
constexpr int N_ROWS = 16384;
constexpr int C_CLS  = 2048;
constexpr int F_DIM  = 512;

typedef __bf16 bf16x8 __attribute__((ext_vector_type(8)));
typedef float  f32x16 __attribute__((ext_vector_type(16)));

// ---------------------------------------------------------------------------
// Fused pre-pass for BOTH inputs: fp32 -> bf16 + exact fp32 row sum-of-squares.
// Blocks [0, N) handle x rows; blocks [N, N+C) handle means rows.
// ---------------------------------------------------------------------------
__global__ __launch_bounds__(256) void prep_rows(
    const float* __restrict__ x,
    const float* __restrict__ means,
    __hip_bfloat162* __restrict__ xb,
    __hip_bfloat162* __restrict__ mb,
    float* __restrict__ xsq,
    float* __restrict__ msq)
{
    int row = blockIdx.x;
    const float* src;
    __hip_bfloat162* dst;
    float* sq;
    if (row < N_ROWS) { src = x; dst = xb; sq = xsq; }
    else { row -= N_ROWS; src = means; dst = mb; sq = msq; }

    const int tid = threadIdx.x;
    const float2 v = ((const float2*)(src + (size_t)row * F_DIM))[tid];

    __hip_bfloat162 p;
    p.x = __float2bfloat16(v.x);
    p.y = __float2bfloat16(v.y);
    dst[(size_t)row * (F_DIM / 2) + tid] = p;

    float ss = v.x * v.x + v.y * v.y;
    #pragma unroll
    for (int off = 32; off > 0; off >>= 1) ss += __shfl_down(ss, off);

    __shared__ float red[4];
    if ((tid & 63) == 0) red[tid >> 6] = ss;
    __syncthreads();
    if (tid == 0) sq[row] = red[0] + red[1] + red[2] + red[3];
}

// ---------------------------------------------------------------------------
// bf16 MFMA NCM kernel, 256x256 block tile (BC=256 classes x BN=256 x-rows),
// BK=64, 512 threads = 8 waves; wave-tile 64(classes) x 128(x-rows) as a
// 2x4 grid of v_mfma_f32_32x32x16_bf16 (A = means, B = x -> D[class][xrow]).
//   * reuse: 6 ds_read_b128 feed 8 MFMA (vs 4:4 at 64x64 wave tiles)
//   * single-barrier async pipeline: global_load_lds copies for tile kt+1
//     issued right after the barrier for kt; drained one full phase later.
//   * operand-swapped epilogue: lane owns output row n = lane&31 with runs of
//     4 consecutive classes -> global_store_dwordx4 (32/lane), float4 msq.
//   * XOR chunk swizzle: chunk c of row r stored at slot c^(r&7).
// LDS = 2*(32+32) KB = 128 KB -> 1 block/CU, 2 waves/SIMD.
// ---------------------------------------------------------------------------
__device__ __forceinline__ void async_copy16(const __hip_bfloat16* g,
                                             __hip_bfloat16* l)
{
    __builtin_amdgcn_global_load_lds(
        (const __attribute__((address_space(1))) unsigned int*)g,
        (__attribute__((address_space(3))) unsigned int*)l,
        16, 0, 0);
}

__global__ __launch_bounds__(512, 2) void ncm_gemm(
    const __hip_bfloat16* __restrict__ xb,   // [N, F] bf16
    const __hip_bfloat16* __restrict__ mb,   // [C, F] bf16
    const float* __restrict__ xsq,           // [N]
    const float* __restrict__ msq,           // [C]
    float* __restrict__ out)                 // [N, C] fp32
{
    constexpr int BC = 256, BN = 256, BK = 64, NKT = F_DIM / BK;

    __shared__ alignas(16) __hip_bfloat16 sM[2][BC * BK];  // 2 x 32 KB (means)
    __shared__ alignas(16) __hip_bfloat16 sX[2][BN * BK];  // 2 x 32 KB (x)

    const int tid  = threadIdx.x;
    const int wave = tid >> 6;        // 0..7
    const int lane = tid & 63;
    const int wc   = wave >> 1;       // 0..3 : class quadrant (64 classes)
    const int wn   = wave & 1;        // 0..1 : x-row half (128 rows)

    const int c0 = blockIdx.x * BC;   // class tile origin
    const int n0 = blockIdx.y * BN;   // x-row tile origin

    // ---- staging: waves 0-3 stage sM (means), waves 4-7 stage sX (x).
    // lane l -> row base+(l>>3), global chunk (l&7)^(l>>3), stored slot l&7
    //   => chunk c of row r lands at slot c^(r&7).
    const int srow   = lane >> 3;
    const int schunk = (lane & 7) ^ srow;
    const bool stA   = (wave < 4);
    const int  sw    = wave & 3;      // 64-row band within the staged operand
    const __hip_bfloat16* gsrc = stA
        ? mb + (size_t)(c0 + sw * 64 + srow) * F_DIM + schunk * 8
        : xb + (size_t)(n0 + sw * 64 + srow) * F_DIM + schunk * 8;
    __hip_bfloat16* ldst[2] = {
        stA ? &sM[0][sw * 64 * BK] : &sX[0][sw * 64 * BK],
        stA ? &sM[1][sw * 64 * BK] : &sX[1][sw * 64 * BK] };

    f32x16 acc[2][4] = {};

    const int lrow  = lane & 31;   // class (A) / x-row (B) index within 32-tile
    const int khalf = lane >> 5;   // which 8-wide half of K=16

    // prologue: stage tile 0 into buffer 0 (8 copies/thread = 64 rows/wave)
    #pragma unroll
    for (int i = 0; i < 8; ++i)
        async_copy16(gsrc + (size_t)i * 8 * F_DIM, ldst[0] + i * 8 * BK);

    for (int kt = 0; kt < NKT; ++kt) {
        const int p = kt & 1;
        __syncthreads();   // drains copies(kt) issued one full phase ago

        if (kt + 1 < NKT) {      // async prefetch tile kt+1 into other buffer
            const int k0n = (kt + 1) * BK;
            __hip_bfloat16* ld = ldst[1 - p];
            #pragma unroll
            for (int i = 0; i < 8; ++i)
                async_copy16(gsrc + (size_t)i * 8 * F_DIM + k0n,
                             ld + i * 8 * BK);
        }

        #pragma unroll
        for (int s = 0; s < 4; ++s) {           // 4 k-steps of 16 within BK=64
            // lane needs chunk 2s+khalf of its row; slot = chunk^(row&7),
            // and row&7 == lane&7 for both operands.
            const int pos = ((2 * s + khalf) ^ (lane & 7)) * 8;
            bf16x8 mf[2], xf[4];
            #pragma unroll
            for (int ct = 0; ct < 2; ++ct)
                mf[ct] = *(const bf16x8*)
                    &sM[p][(wc * 64 + ct * 32 + lrow) * BK + pos];
            #pragma unroll
            for (int nt = 0; nt < 4; ++nt)
                xf[nt] = *(const bf16x8*)
                    &sX[p][(wn * 128 + nt * 32 + lrow) * BK + pos];
            #pragma unroll
            for (int ct = 0; ct < 2; ++ct)
                #pragma unroll
                for (int nt = 0; nt < 4; ++nt)
                    acc[ct][nt] = __builtin_amdgcn_mfma_f32_32x32x16_bf16(
                        mf[ct], xf[nt], acc[ct][nt], 0, 0, 0);
        }
    }

    // ---- epilogue: D[class][xrow]; col (xrow) = lane&31 -> fixed output row,
    // rows (classes) = (r&3) + 8*(r>>2) + 4*khalf -> runs of 4 consecutive
    // classes per reg-group g = r>>2  =>  float4 stores.
    float xq[4];
    #pragma unroll
    for (int nt = 0; nt < 4; ++nt)
        xq[nt] = xsq[n0 + wn * 128 + nt * 32 + lrow];

    #pragma unroll
    for (int ct = 0; ct < 2; ++ct) {
        const int cb = c0 + wc * 64 + ct * 32 + 4 * khalf;
        #pragma unroll
        for (int g = 0; g < 4; ++g) {
            const int cg = cb + 8 * g;
            const float4 mq = *(const float4*)&msq[cg];
            #pragma unroll
            for (int nt = 0; nt < 4; ++nt) {
                const int n = n0 + wn * 128 + nt * 32 + lrow;
                float4 o;
                o.x = -sqrtf(fmaxf(xq[nt] + mq.x - 2.0f * acc[ct][nt][4*g+0], 0.0f));
                o.y = -sqrtf(fmaxf(xq[nt] + mq.y - 2.0f * acc[ct][nt][4*g+1], 0.0f));
                o.z = -sqrtf(fmaxf(xq[nt] + mq.z - 2.0f * acc[ct][nt][4*g+2], 0.0f));
                o.w = -sqrtf(fmaxf(xq[nt] + mq.w - 2.0f * acc[ct][nt][4*g+3], 0.0f));
                *(float4*)&out[(size_t)n * C_CLS + cg] = o;
            }
        }
    }
}

// ---------------------------------------------------------------------------
extern "C" void kernel_launch(void* const* d_in, const int* in_sizes, int n_in,
                              void* d_out, int out_size, void* d_ws,
                              size_t ws_size, hipStream_t stream)
{
    const float* x     = (const float*)d_in[0];   // [N, F]
    const float* means = (const float*)d_in[1];   // [C, F]
    float* out = (float*)d_out;                   // [N, C]

    char* ws = (char*)d_ws;
    __hip_bfloat16* xb = (__hip_bfloat16*)ws;                         // 16 MB
    __hip_bfloat16* mb = (__hip_bfloat16*)(ws + (size_t)N_ROWS * F_DIM * 2);
    float* xsq = (float*)(ws + (size_t)(N_ROWS + C_CLS) * F_DIM * 2);
    float* msq = xsq + N_ROWS;

    prep_rows<<<N_ROWS + C_CLS, 256, 0, stream>>>(
        x, means, (__hip_bfloat162*)xb, (__hip_bfloat162*)mb, xsq, msq);

    dim3 grid(C_CLS / 256, N_ROWS / 256);   // 8 x 64 = 512 blocks
    ncm_gemm<<<grid, 512, 0, stream>>>(xb, mb, xsq, msq, out);
}

// Round 6
// 198.268 us; speedup vs baseline: 1.2850x; 1.2850x over previous
//
#include <hip/hip_runtime.h>
#include <hip/hip_bf16.h>

// Problem constants (reference: N=16384, C=2048, F=512; fp32 in/out).
constexpr int N_ROWS = 16384;
constexpr int C_CLS  = 2048;
constexpr int F_DIM  = 512;

typedef __bf16 bf16x8 __attribute__((ext_vector_type(8)));
typedef float  f32x16 __attribute__((ext_vector_type(16)));

// ---------------------------------------------------------------------------
// Fused pre-pass for BOTH inputs: fp32 -> bf16 + exact fp32 row sum-of-squares.
// Blocks [0, N) handle x rows; blocks [N, N+C) handle means rows.
// ---------------------------------------------------------------------------
__global__ __launch_bounds__(256) void prep_rows(
    const float* __restrict__ x,
    const float* __restrict__ means,
    __hip_bfloat162* __restrict__ xb,
    __hip_bfloat162* __restrict__ mb,
    float* __restrict__ xsq,
    float* __restrict__ msq)
{
    int row = blockIdx.x;
    const float* src;
    __hip_bfloat162* dst;
    float* sq;
    if (row < N_ROWS) { src = x; dst = xb; sq = xsq; }
    else { row -= N_ROWS; src = means; dst = mb; sq = msq; }

    const int tid = threadIdx.x;
    const float2 v = ((const float2*)(src + (size_t)row * F_DIM))[tid];

    __hip_bfloat162 p;
    p.x = __float2bfloat16(v.x);
    p.y = __float2bfloat16(v.y);
    dst[(size_t)row * (F_DIM / 2) + tid] = p;

    float ss = v.x * v.x + v.y * v.y;
    #pragma unroll
    for (int off = 32; off > 0; off >>= 1) ss += __shfl_down(ss, off);

    __shared__ float red[4];
    if ((tid & 63) == 0) red[tid >> 6] = ss;
    __syncthreads();
    if (tid == 0) sq[row] = red[0] + red[1] + red[2] + red[3];
}

// ---------------------------------------------------------------------------
// bf16 MFMA NCM kernel — 128x128 tile, BK=32, single-barrier async pipeline.
// Design (round 6):
//   * BK=32 halves LDS (2x(8+8)=32 KB) -> 4-5 blocks/CU co-resident; 16 fine
//     kt phases interleave resident blocks' MFMA / staging / LDS pipes
//     (rounds 1-5 showed sum-mode ~1630 cyc/block-kt; goal is max-mode).
//   * XCD swizzle: band = id&127, ctile = id>>7 => the 16 class-tiles of one
//     x-band share id%8 (same XCD) -> x-band fetched into one L2, reused 16x.
//   * LDS chunk swizzle: chunk c of row r stored at slot c^((r>>1)&3) ->
//     ds_read_b128 16-lane phases hit all 8 (parity,slot) bank-quads evenly
//     (2-way = free, vs 4-way in rounds 1-5).
//   * Single barrier per kt: copies for kt+1 issued right after barrier(kt),
//     drained one full compute phase later.
// ---------------------------------------------------------------------------
__device__ __forceinline__ void async_copy16(const __hip_bfloat16* g,
                                             __hip_bfloat16* l)
{
    __builtin_amdgcn_global_load_lds(
        (const __attribute__((address_space(1))) unsigned int*)g,
        (__attribute__((address_space(3))) unsigned int*)l,
        16, 0, 0);
}

__global__ __launch_bounds__(256) void ncm_gemm(
    const __hip_bfloat16* __restrict__ xb,   // [N, F] bf16
    const __hip_bfloat16* __restrict__ mb,   // [C, F] bf16
    const float* __restrict__ xsq,           // [N]
    const float* __restrict__ msq,           // [C]
    float* __restrict__ out)                 // [N, C] fp32
{
    constexpr int BK = 32, NKT = F_DIM / BK;   // 16 k-tiles

    __shared__ alignas(16) __hip_bfloat16 sA[2][128 * BK];  // 2 x 8 KB (x)
    __shared__ alignas(16) __hip_bfloat16 sB[2][128 * BK];  // 2 x 8 KB (means)

    const int tid  = threadIdx.x;
    const int wave = tid >> 6;        // 0..3
    const int lane = tid & 63;
    const int wm   = wave >> 1;       // wave row (2x2)
    const int wn   = wave & 1;        // wave col

    // XCD-aware decode: all 16 class-tiles of a band share blockIdx%8.
    const int band  = blockIdx.x & 127;   // x-row band   (0..127)
    const int ctile = blockIdx.x >> 7;    // class tile   (0..15)
    const int row0 = band * 128;          // over N (x rows)
    const int col0 = ctile * 128;         // over C (classes)

    // ---- staging: one copy instr = 16 rows x 4 chunks of 16 B.
    // lane l -> row l>>2, slot l&3, carries global chunk (l&3)^((l>>3)&3)
    //   => chunk c of row r lands at slot c^((r>>1)&3).
    const int srow   = lane >> 2;                       // 0..15
    const int schunk = (lane & 3) ^ ((lane >> 3) & 3);  // swizzled chunk
    const __hip_bfloat16* gA =
        xb + (size_t)(row0 + wave * 32 + srow) * F_DIM + schunk * 8;
    const __hip_bfloat16* gB =
        mb + (size_t)(col0 + wave * 32 + srow) * F_DIM + schunk * 8;

    f32x16 acc[2][2] = {};

    const int lrow  = lane & 31;   // A row (m) / B col (n) within 32-tile
    const int khalf = lane >> 5;   // which 8-wide half of K=16
    const int rsw   = (lrow >> 1) & 3;   // read-side swizzle key

    // prologue: stage tile 0 into buffer 0 (wave stages its 32-row band,
    // 2 instrs per operand)
    #pragma unroll
    for (int i = 0; i < 2; ++i) {
        async_copy16(gA + (size_t)i * 16 * F_DIM,
                     &sA[0][(wave * 32 + i * 16) * BK]);
        async_copy16(gB + (size_t)i * 16 * F_DIM,
                     &sB[0][(wave * 32 + i * 16) * BK]);
    }

    for (int kt = 0; kt < NKT; ++kt) {
        const int p = kt & 1;
        __syncthreads();   // drains copies(kt) issued one full phase ago

        if (kt + 1 < NKT) {      // async prefetch tile kt+1 into other buffer
            const int k0n = (kt + 1) * BK;
            #pragma unroll
            for (int i = 0; i < 2; ++i) {
                async_copy16(gA + (size_t)i * 16 * F_DIM + k0n,
                             &sA[1 - p][(wave * 32 + i * 16) * BK]);
                async_copy16(gB + (size_t)i * 16 * F_DIM + k0n,
                             &sB[1 - p][(wave * 32 + i * 16) * BK]);
            }
        }

        #pragma unroll
        for (int s = 0; s < 2; ++s) {           // 2 k-steps of 16 within BK=32
            // lane needs chunk 2s+khalf of its row; slot = chunk^((row>>1)&3);
            // row>>1 & 3 == lrow>>1 & 3 (tile offsets are multiples of 32).
            const int pos = ((2 * s + khalf) ^ rsw) * 8;
            bf16x8 af[2], bfr[2];
            #pragma unroll
            for (int mt = 0; mt < 2; ++mt)
                af[mt] = *(const bf16x8*)
                    &sA[p][(wm * 64 + mt * 32 + lrow) * BK + pos];
            #pragma unroll
            for (int nt = 0; nt < 2; ++nt)
                bfr[nt] = *(const bf16x8*)
                    &sB[p][(wn * 64 + nt * 32 + lrow) * BK + pos];
            #pragma unroll
            for (int mt = 0; mt < 2; ++mt)
                #pragma unroll
                for (int nt = 0; nt < 2; ++nt)
                    acc[mt][nt] = __builtin_amdgcn_mfma_f32_32x32x16_bf16(
                        af[mt], bfr[nt], acc[mt][nt], 0, 0, 0);
        }
    }

    // ---- epilogue: 32x32 C/D layout col=lane&31, row=(r&3)+8*(r>>2)+4*khalf
    // (scalar column-coalesced stores: measured exactly 131 MB HBM writes)
    #pragma unroll
    for (int mt = 0; mt < 2; ++mt) {
        const int rbase = row0 + wm * 64 + mt * 32 + 4 * khalf;
        float xs[16];
        #pragma unroll
        for (int r = 0; r < 16; ++r)
            xs[r] = xsq[rbase + (r & 3) + 8 * (r >> 2)];
        #pragma unroll
        for (int nt = 0; nt < 2; ++nt) {
            const int col = col0 + wn * 64 + nt * 32 + lrow;
            const float ms = msq[col];
            #pragma unroll
            for (int r = 0; r < 16; ++r) {
                const int row = rbase + (r & 3) + 8 * (r >> 2);
                const float d2 =
                    fmaxf(xs[r] + ms - 2.0f * acc[mt][nt][r], 0.0f);
                out[(size_t)row * C_CLS + col] = -sqrtf(d2);
            }
        }
    }
}

// ---------------------------------------------------------------------------
extern "C" void kernel_launch(void* const* d_in, const int* in_sizes, int n_in,
                              void* d_out, int out_size, void* d_ws,
                              size_t ws_size, hipStream_t stream)
{
    const float* x     = (const float*)d_in[0];   // [N, F]
    const float* means = (const float*)d_in[1];   // [C, F]
    float* out = (float*)d_out;                   // [N, C]

    char* ws = (char*)d_ws;
    __hip_bfloat16* xb = (__hip_bfloat16*)ws;                         // 16 MB
    __hip_bfloat16* mb = (__hip_bfloat16*)(ws + (size_t)N_ROWS * F_DIM * 2);
    float* xsq = (float*)(ws + (size_t)(N_ROWS + C_CLS) * F_DIM * 2);
    float* msq = xsq + N_ROWS;

    prep_rows<<<N_ROWS + C_CLS, 256, 0, stream>>>(
        x, means, (__hip_bfloat162*)xb, (__hip_bfloat162*)mb, xsq, msq);

    ncm_gemm<<<dim3(2048), 256, 0, stream>>>(xb, mb, xsq, msq, out);
}